// Round 1
// baseline (590.362 us; speedup 1.0000x reference)
//
#include <hip/hip_runtime.h>

#define NB   4096
#define SS   102
#define SSP  104
#define HID  8
#define NH   2
#define HD   4
#define RS   0.72134752044448170368f   // 0.5 * log2(e): score scale folded into q

typedef float v2f __attribute__((ext_vector_type(2)));

// Bank-group-spreading row permutation, bijective on [0,104):
// consecutive rows land 13 f4-slots apart -> reads of rows {8j+w} hit distinct bank groups.
__device__ __forceinline__ int PIDX(int r) { return (r & 7) * 13 + (r >> 3); }

template<int CTRL>
__device__ __forceinline__ float dppf(float x) {
    return __builtin_bit_cast(float,
        __builtin_amdgcn_mov_dpp(__builtin_bit_cast(int, x), CTRL, 0xF, 0xF, true));
}
template<int CTRL>
__device__ __forceinline__ v2f dpp2(v2f x) {
    v2f r; r.x = dppf<CTRL>(x.x); r.y = dppf<CTRL>(x.y); return r;
}

// 8 projected dims for 2 rows (v2f across rows). W is a wave-uniform kernel-arg
// pointer with compile-time indices -> compiler emits s_load (weights live in SGPRs).
__device__ __forceinline__ void proj8(const float4& a0, const float4& a1,
                                      const float4& b0, const float4& b1,
                                      const float* __restrict__ W, v2f x[8]) {
    v2f in[8] = { {a0.x,b0.x},{a0.y,b0.y},{a0.z,b0.z},{a0.w,b0.w},
                  {a1.x,b1.x},{a1.y,b1.y},{a1.z,b1.z},{a1.w,b1.w} };
#pragma unroll
    for (int i = 0; i < 8; ++i) {
        v2f acc = in[0] * W[i*8+0];
#pragma unroll
        for (int j = 1; j < 8; ++j) acc += in[j] * W[i*8+j];
        x[i] = acc;
    }
}

// LDS (10.8 KB total):
//  sQ : [2][52 pairs][8]  rotated+pre-scaled q, pair-major: (d0r0,d0r1,d1r0,d1r1,d2..,d3..)
//       pair index permuted by PJ(p)=(p&3)*13+(p>>2).  REUSED as comb [2][PIDX(row)][4].
//  sK : [2][PIDX(row)][4] rotated k (rows 102,103 zero pad)
//  sV : [2][PIDX(row)][4] projected v (rows 102,103 zero pad)
//  sRot: [row][sin,cos]
__global__ __launch_bounds__(256, 4) void mha_fused_kernel(
    const float* __restrict__ query, const float* __restrict__ key,
    const float* __restrict__ value, const float* __restrict__ wq,
    const float* __restrict__ wk, const float* __restrict__ wv,
    const float* __restrict__ wo, float* __restrict__ out)
{
    __shared__ float sQ[NH * 52 * 8];       // 832 floats
    __shared__ float sK[NH * SSP * HD];     // 832
    __shared__ float sV[NH * SSP * HD];     // 832
    __shared__ float sRot[SSP * 2];         // 208

    const int t    = threadIdx.x;
    const int b    = blockIdx.x;
    const int wid  = t >> 6;
    const int lane = t & 63;

    // ---------------- phase 0: issue global row loads; rot table; zero pads ----------------
    float4 a0, a1, b0, b1;
    if (wid < 3 && lane < 51) {
        const float* src = (wid == 0) ? query : (wid == 1) ? key : value;
        const float4* s4 = (const float4*)(src + (size_t)b * (SS * HID));
        a0 = s4[4*lane]; a1 = s4[4*lane+1]; b0 = s4[4*lane+2]; b1 = s4[4*lane+3];
    }
    if (t < SS) sRot[2*t] = sinf((float)t);
    if (t >= 128 && t < 128 + SS) { const int s = t - 128; sRot[2*s+1] = cosf((float)s); }
    if (t >= 208) {
        const int z = t - 208;                 // 0..47
        if (z < 16) {                          // q pad pair 51 (rows 102,103), both heads
            sQ[(z >> 3) * 416 + 408 + (z & 7)] = 0.f;
        } else {                               // k/v pad rows 102,103
            const int rem = z & 15;
            const int h = rem >> 3, r = SS + ((rem >> 2) & 1), d = rem & 3;
            float* dst = (z < 32) ? sK : sV;
            dst[(h * SSP + PIDX(r)) * HD + d] = 0.f;
        }
    }
    __syncthreads();

    // ---------------- phase 1: projections (wave0: q+rot, wave1: k+rot, wave2: v) ----------
    if (wid < 3 && lane < 51) {
        const int r0 = 2 * lane;
        v2f x[8];
        if (wid == 0)      proj8(a0, a1, b0, b1, wq, x);
        else if (wid == 1) proj8(a0, a1, b0, b1, wk, x);
        else               proj8(a0, a1, b0, b1, wv, x);

        if (wid < 2) {
            // reference broadcast quirk: head0 scaled by sin(s), head1 by cos(s);
            // pair: e' = (e - o)*w, o' = (o + e)*w.  q additionally folds 0.5*log2(e).
            const v2f rc0 = *(const v2f*)(sRot + 2*r0);
            const v2f rc1 = *(const v2f*)(sRot + 2*r0 + 2);
            v2f sn = { rc0.x, rc1.x };
            v2f cs = { rc0.y, rc1.y };
            if (wid == 0) { sn *= RS; cs *= RS; }
            const v2f y0 = (x[0]-x[1])*sn, y1 = (x[1]+x[0])*sn;
            const v2f y2 = (x[2]-x[3])*sn, y3 = (x[3]+x[2])*sn;
            const v2f y4 = (x[4]-x[5])*cs, y5 = (x[5]+x[4])*cs;
            const v2f y6 = (x[6]-x[7])*cs, y7 = (x[7]+x[6])*cs;
            if (wid == 0) {
                const int pj = (lane & 3) * 13 + (lane >> 2);   // PJ(pair)
                float4* d = (float4*)sQ;
                d[2*pj]       = make_float4(y0.x, y0.y, y1.x, y1.y);
                d[2*pj+1]     = make_float4(y2.x, y2.y, y3.x, y3.y);
                d[104+2*pj]   = make_float4(y4.x, y4.y, y5.x, y5.y);
                d[104+2*pj+1] = make_float4(y6.x, y6.y, y7.x, y7.y);
            } else {
                const int i0 = PIDX(r0), i1 = PIDX(r0 + 1);
                float4* d = (float4*)sK;
                d[i0]      = make_float4(y0.x, y1.x, y2.x, y3.x);
                d[SSP+i0]  = make_float4(y4.x, y5.x, y6.x, y7.x);
                d[i1]      = make_float4(y0.y, y1.y, y2.y, y3.y);
                d[SSP+i1]  = make_float4(y4.y, y5.y, y6.y, y7.y);
            }
        } else {
            const int i0 = PIDX(r0), i1 = PIDX(r0 + 1);
            float4* d = (float4*)sV;
            d[i0]      = make_float4(x[0].x, x[1].x, x[2].x, x[3].x);
            d[SSP+i0]  = make_float4(x[4].x, x[5].x, x[6].x, x[7].x);
            d[i1]      = make_float4(x[0].y, x[1].y, x[2].y, x[3].y);
            d[SSP+i1]  = make_float4(x[4].y, x[5].y, x[6].y, x[7].y);
        }
    }
    __syncthreads();

    // ---------------- phase 2: attention (waves 0,1; h = wid) ----------------
    // lane = (qp, w): qp = lane>>2 owns 8 q-rows (4 v2f pairs), w = lane&3 owns
    // keys == w (mod 4).  13 iterations x 2 keys; all K/V ds_reads are 4-address
    // group-spread b128s instead of 1-address broadcasts.
    const int qp = lane >> 2, w = lane & 3;
    if (wid < 2 && qp < 13) {
        const int h = wid;
        v2f q[4][4];
        {
            const float4* Q4 = (const float4*)sQ + h * 104;
#pragma unroll
            for (int pp = 0; pp < 4; ++pp) {
                const float4 f0 = Q4[2*(pp*13+qp)];
                const float4 f1 = Q4[2*(pp*13+qp)+1];
                q[pp][0] = (v2f){f0.x, f0.y}; q[pp][1] = (v2f){f0.z, f0.w};
                q[pp][2] = (v2f){f1.x, f1.y}; q[pp][3] = (v2f){f1.z, f1.w};
            }
        }
        v2f acc[4][4], l[4];
#pragma unroll
        for (int pp = 0; pp < 4; ++pp) {
            l[pp] = (v2f){0.f, 0.f};
#pragma unroll
            for (int d = 0; d < 4; ++d) acc[pp][d] = (v2f){0.f, 0.f};
        }
        const float4* Ka = (const float4*)sK + h*SSP + 13*w;   // keys 8j+w   -> PIDX = 13w+j
        const float4* Kb = Ka + 52;                            // keys 8j+4+w -> PIDX = 13(w+4)+j
        const float4* Va = (const float4*)sV + h*SSP + 13*w;
        const float4* Vb = Va + 52;
        for (int j = 0; j < 13; ++j) {
            const float4 ka = Ka[j], va = Va[j];
            const float4 kb = Kb[j], vb = Vb[j];
#pragma unroll
            for (int pp = 0; pp < 4; ++pp) {
                v2f s = q[pp][0]*ka.x + q[pp][1]*ka.y + q[pp][2]*ka.z + q[pp][3]*ka.w;
                v2f p; p.x = __builtin_amdgcn_exp2f(s.x); p.y = __builtin_amdgcn_exp2f(s.y);
                l[pp] += p;
                acc[pp][0] += p*va.x; acc[pp][1] += p*va.y;
                acc[pp][2] += p*va.z; acc[pp][3] += p*va.w;
            }
#pragma unroll
            for (int pp = 0; pp < 4; ++pp) {
                v2f s = q[pp][0]*kb.x + q[pp][1]*kb.y + q[pp][2]*kb.z + q[pp][3]*kb.w;
                v2f p; p.x = __builtin_amdgcn_exp2f(s.x); p.y = __builtin_amdgcn_exp2f(s.y);
                l[pp] += p;
                acc[pp][0] += p*vb.x; acc[pp][1] += p*vb.y;
                acc[pp][2] += p*vb.z; acc[pp][3] += p*vb.w;
            }
        }
        // pad keys 102,103 (zero K rows) contributed exp2(0)=1 to l in lanes w>=2
        if (w >= 2) {
#pragma unroll
            for (int pp = 0; pp < 4; ++pp) l[pp] -= (v2f){1.f, 1.f};
        }
        // quad butterfly over the 4 key residues (pure VALU, no LDS round-trip)
#pragma unroll
        for (int pp = 0; pp < 4; ++pp) {
            l[pp] += dpp2<0xB1>(l[pp]);                       // quad_perm [1,0,3,2]
#pragma unroll
            for (int d = 0; d < 4; ++d) acc[pp][d] += dpp2<0xB1>(acc[pp][d]);
        }
#pragma unroll
        for (int pp = 0; pp < 4; ++pp) {
            l[pp] += dpp2<0x4E>(l[pp]);                       // quad_perm [2,3,0,1]
#pragma unroll
            for (int d = 0; d < 4; ++d) acc[pp][d] += dpp2<0x4E>(acc[pp][d]);
        }
        // lane w writes its pair (static branches -> no runtime register indexing).
        // comb overlays sQ[h] (q reads for this head finished above, same wave).
        float4* comb = (float4*)sQ + h * 104;
#define WRITE_PAIR(P) { \
            const float ix = __builtin_amdgcn_rcpf(l[P].x); \
            const float iy = __builtin_amdgcn_rcpf(l[P].y); \
            const int r0 = 8*qp + 2*(P); \
            comb[PIDX(r0)]   = make_float4(acc[P][0].x*ix, acc[P][1].x*ix, acc[P][2].x*ix, acc[P][3].x*ix); \
            comb[PIDX(r0+1)] = make_float4(acc[P][0].y*iy, acc[P][1].y*iy, acc[P][2].y*iy, acc[P][3].y*iy); \
        }
        if      (w == 0) WRITE_PAIR(0)
        else if (w == 1) WRITE_PAIR(1)
        else if (w == 2) WRITE_PAIR(2)
        else             WRITE_PAIR(3)
#undef WRITE_PAIR
    }
    __syncthreads();

    // ---------------- phase 3: output projection (wo in SGPRs) ----------------
    const int row = wid * 26 + lane;
    if (lane < 26 && row < SS) {
        const float4 c0 = ((const float4*)sQ)[PIDX(row)];        // head 0
        const float4 c1 = ((const float4*)sQ)[104 + PIDX(row)];  // head 1
        float o[8];
#pragma unroll
        for (int i = 0; i < 8; ++i) {
            const float* wr = wo + i*8;
            o[i] = c0.x*wr[0] + c0.y*wr[1] + c0.z*wr[2] + c0.w*wr[3]
                 + c1.x*wr[4] + c1.y*wr[5] + c1.z*wr[6] + c1.w*wr[7];
        }
        float4* o4 = (float4*)(out + (size_t)b * (SS * HID) + row * HID);
        o4[0] = make_float4(o[0], o[1], o[2], o[3]);
        o4[1] = make_float4(o[4], o[5], o[6], o[7]);
    }
}

extern "C" void kernel_launch(void* const* d_in, const int* in_sizes, int n_in,
                              void* d_out, int out_size, void* d_ws, size_t ws_size,
                              hipStream_t stream) {
    const float* query = (const float*)d_in[0];
    const float* key   = (const float*)d_in[1];
    const float* value = (const float*)d_in[2];
    const float* wq    = (const float*)d_in[3];
    const float* wk    = (const float*)d_in[4];
    const float* wv    = (const float*)d_in[5];
    const float* wo    = (const float*)d_in[6];
    float* out = (float*)d_out;
    mha_fused_kernel<<<NB, 256, 0, stream>>>(query, key, value, wq, wk, wv, wo, out);
}

// Round 2
// 140.750 us; speedup vs baseline: 4.1944x; 4.1944x over previous
//
#include <hip/hip_runtime.h>

#define NB   4096
#define SS   102
#define SSP  104
#define HID  8
#define NH   2
#define HD   4
#define RS   0.72134752044448170368f   // 0.5 * log2(e): score scale folded into q

typedef float v2f __attribute__((ext_vector_type(2)));

// Bank-group-spreading row permutation for K/V, bijective on [0,104):
// keys 8j+w land at 13w+j -> a wave's 4 residue-lanes read 4 spread addresses.
__device__ __forceinline__ int PIDX(int r) { return (r & 7) * 13 + (r >> 3); }

template<int CTRL>
__device__ __forceinline__ float dppf(float x) {
    return __builtin_bit_cast(float,
        __builtin_amdgcn_mov_dpp(__builtin_bit_cast(int, x), CTRL, 0xF, 0xF, true));
}
template<int CTRL>
__device__ __forceinline__ v2f dpp2(v2f x) {
    v2f r; r.x = dppf<CTRL>(x.x); r.y = dppf<CTRL>(x.y); return r;
}

// 8 projected dims for 2 rows (v2f across rows). W is a wave-uniform kernel-arg
// pointer with compile-time indices -> compiler emits s_load (weights in SGPRs).
__device__ __forceinline__ void proj8(const float4& a0, const float4& a1,
                                      const float4& b0, const float4& b1,
                                      const float* __restrict__ W, v2f x[8]) {
    v2f in[8] = { {a0.x,b0.x},{a0.y,b0.y},{a0.z,b0.z},{a0.w,b0.w},
                  {a1.x,b1.x},{a1.y,b1.y},{a1.z,b1.z},{a1.w,b1.w} };
#pragma unroll
    for (int i = 0; i < 8; ++i) {
        v2f acc = in[0] * W[i*8+0];
#pragma unroll
        for (int j = 1; j < 8; ++j) acc += in[j] * W[i*8+j];
        x[i] = acc;
    }
}

// LDS (~14 KB):
//  sQ : [2 heads][52 pairs][2 float4]  pair-major rotated+pre-scaled q, LINEAR pair idx.
//       float4 2p   = dims 0,1 x rows {2p,2p+1}; float4 2p+1 = dims 2,3.
//       pair 51 (rows 102,103) is zero pad.
//  sK : [2][PIDX(row)][4] rotated k (rows 102,103 zero pad)
//  sV : [2][PIDX(row)][4] projected v (rows 102,103 zero pad)
//  sC : [2][row][4] head-combined attention output, linear rows
//  sRot: [row][sin,cos]
__global__ __launch_bounds__(256) void mha_fused_kernel(
    const float* __restrict__ query, const float* __restrict__ key,
    const float* __restrict__ value, const float* __restrict__ wq,
    const float* __restrict__ wk, const float* __restrict__ wv,
    const float* __restrict__ wo, float* __restrict__ out)
{
    __shared__ float sQ[NH * 52 * 8];       // 832 floats
    __shared__ float sK[NH * SSP * HD];     // 832
    __shared__ float sV[NH * SSP * HD];     // 832
    __shared__ float sC[NH * SSP * HD];     // 832
    __shared__ float sRot[SSP * 2];         // 208

    const int t    = threadIdx.x;
    const int b    = blockIdx.x;
    const int wid  = t >> 6;
    const int lane = t & 63;

    // ---------------- phase 0: global row loads; rot table; zero pads ----------------
    float4 a0, a1, b0, b1;
    if (wid < 3 && lane < 51) {
        const float* src = (wid == 0) ? query : (wid == 1) ? key : value;
        const float4* s4 = (const float4*)(src + (size_t)b * (SS * HID));
        a0 = s4[4*lane]; a1 = s4[4*lane+1]; b0 = s4[4*lane+2]; b1 = s4[4*lane+3];
    }
    if (t < SS) sRot[2*t] = sinf((float)t);
    if (t >= 128 && t < 128 + SS) { const int s = t - 128; sRot[2*s+1] = cosf((float)s); }
    if (t >= 208) {
        const int z = t - 208;                 // 0..47
        if (z < 16) {                          // q pad pair 51 (rows 102,103), both heads
            sQ[(z >> 3) * 416 + 408 + (z & 7)] = 0.f;
        } else {                               // k/v pad rows 102,103
            const int rem = z & 15;
            const int h = rem >> 3, r = SS + ((rem >> 2) & 1), d = rem & 3;
            float* dst = (z < 32) ? sK : sV;
            dst[(h * SSP + PIDX(r)) * HD + d] = 0.f;
        }
    }
    __syncthreads();

    // ---------------- phase 1: projections (wave0: q+rot, wave1: k+rot, wave2: v) ----------
    if (wid < 3 && lane < 51) {
        const int r0 = 2 * lane;
        v2f x[8];
        if (wid == 0)      proj8(a0, a1, b0, b1, wq, x);
        else if (wid == 1) proj8(a0, a1, b0, b1, wk, x);
        else               proj8(a0, a1, b0, b1, wv, x);

        if (wid < 2) {
            // reference broadcast quirk: head0 scaled by sin(s), head1 by cos(s);
            // pair: e' = (e - o)*w, o' = (o + e)*w.  q additionally folds 0.5*log2(e).
            const v2f rc0 = *(const v2f*)(sRot + 2*r0);
            const v2f rc1 = *(const v2f*)(sRot + 2*r0 + 2);
            v2f sn = { rc0.x, rc1.x };
            v2f cs = { rc0.y, rc1.y };
            if (wid == 0) { sn *= RS; cs *= RS; }
            const v2f y0 = (x[0]-x[1])*sn, y1 = (x[1]+x[0])*sn;
            const v2f y2 = (x[2]-x[3])*sn, y3 = (x[3]+x[2])*sn;
            const v2f y4 = (x[4]-x[5])*cs, y5 = (x[5]+x[4])*cs;
            const v2f y6 = (x[6]-x[7])*cs, y7 = (x[7]+x[6])*cs;
            if (wid == 0) {
                const int p = lane;                 // pair index, LINEAR
                float4* d = (float4*)sQ;
                d[2*p]       = make_float4(y0.x, y0.y, y1.x, y1.y);
                d[2*p+1]     = make_float4(y2.x, y2.y, y3.x, y3.y);
                d[104+2*p]   = make_float4(y4.x, y4.y, y5.x, y5.y);
                d[104+2*p+1] = make_float4(y6.x, y6.y, y7.x, y7.y);
            } else {
                const int i0 = PIDX(r0), i1 = PIDX(r0 + 1);
                float4* d = (float4*)sK;
                d[i0]      = make_float4(y0.x, y1.x, y2.x, y3.x);
                d[SSP+i0]  = make_float4(y4.x, y5.x, y6.x, y7.x);
                d[i1]      = make_float4(y0.y, y1.y, y2.y, y3.y);
                d[SSP+i1]  = make_float4(y4.y, y5.y, y6.y, y7.y);
            }
        } else {
            const int i0 = PIDX(r0), i1 = PIDX(r0 + 1);
            float4* d = (float4*)sV;
            d[i0]      = make_float4(x[0].x, x[1].x, x[2].x, x[3].x);
            d[SSP+i0]  = make_float4(x[4].x, x[5].x, x[6].x, x[7].x);
            d[i1]      = make_float4(x[0].y, x[1].y, x[2].y, x[3].y);
            d[SSP+i1]  = make_float4(x[4].y, x[5].y, x[6].y, x[7].y);
        }
    }
    __syncthreads();

    // ---------------- phase 2: attention, ALL 4 waves. wave = (head, q-half) -------------
    // lane = (qp, w): qp = lane>>2 (0..12) owns q-pairs {qh*26+2qp, +1} (4 rows);
    // w = lane&3 owns keys == w (mod 4): 13 iters x 2 keys, 4-address spread b128 reads.
    // Per-lane state: q[2][4]+acc[2][4]+l[2] v2f = 36 VGPRs (half of round-1's blowup).
    const int qp = lane >> 2, w = lane & 3;
    if (qp < 13) {
        const int h  = wid >> 1;
        const int qh = wid & 1;
        const int pbase = qh * 26 + 2 * qp;       // first of 2 pairs
        v2f q[2][4];
        {
            const float4* Q4 = (const float4*)sQ + h * 104;
#pragma unroll
            for (int P = 0; P < 2; ++P) {
                const float4 f0 = Q4[2*(pbase+P)];
                const float4 f1 = Q4[2*(pbase+P)+1];
                q[P][0] = (v2f){f0.x, f0.y}; q[P][1] = (v2f){f0.z, f0.w};
                q[P][2] = (v2f){f1.x, f1.y}; q[P][3] = (v2f){f1.z, f1.w};
            }
        }
        v2f acc[2][4], l[2];
#pragma unroll
        for (int P = 0; P < 2; ++P) {
            l[P] = (v2f){0.f, 0.f};
#pragma unroll
            for (int d = 0; d < 4; ++d) acc[P][d] = (v2f){0.f, 0.f};
        }
        const float4* Ka = (const float4*)sK + h*SSP + 13*w;   // keys 8j+w   -> PIDX = 13w+j
        const float4* Kb = Ka + 52;                            // keys 8j+4+w -> PIDX = 13(w+4)+j
        const float4* Va = (const float4*)sV + h*SSP + 13*w;
        const float4* Vb = Va + 52;
        for (int j = 0; j < 13; ++j) {
            const float4 ka = Ka[j], va = Va[j];
            const float4 kb = Kb[j], vb = Vb[j];
#pragma unroll
            for (int P = 0; P < 2; ++P) {
                v2f s = q[P][0]*ka.x + q[P][1]*ka.y + q[P][2]*ka.z + q[P][3]*ka.w;
                v2f p; p.x = __builtin_amdgcn_exp2f(s.x); p.y = __builtin_amdgcn_exp2f(s.y);
                l[P] += p;
                acc[P][0] += p*va.x; acc[P][1] += p*va.y;
                acc[P][2] += p*va.z; acc[P][3] += p*va.w;
            }
#pragma unroll
            for (int P = 0; P < 2; ++P) {
                v2f s = q[P][0]*kb.x + q[P][1]*kb.y + q[P][2]*kb.z + q[P][3]*kb.w;
                v2f p; p.x = __builtin_amdgcn_exp2f(s.x); p.y = __builtin_amdgcn_exp2f(s.y);
                l[P] += p;
                acc[P][0] += p*vb.x; acc[P][1] += p*vb.y;
                acc[P][2] += p*vb.z; acc[P][3] += p*vb.w;
            }
        }
        // pad keys 102,103 (zero K rows, exp2(0)=1) landed in residues w=2 (Kb) and w=3 (Kb)
        if (w >= 2) { l[0] -= (v2f){1.f, 1.f}; l[1] -= (v2f){1.f, 1.f}; }
        // quad butterfly over the 4 key residues (pure VALU, no LDS round-trip)
#pragma unroll
        for (int P = 0; P < 2; ++P) {
            l[P] += dpp2<0xB1>(l[P]);                       // quad_perm [1,0,3,2]
#pragma unroll
            for (int d = 0; d < 4; ++d) acc[P][d] += dpp2<0xB1>(acc[P][d]);
        }
#pragma unroll
        for (int P = 0; P < 2; ++P) {
            l[P] += dpp2<0x4E>(l[P]);                       // quad_perm [2,3,0,1]
#pragma unroll
            for (int d = 0; d < 4; ++d) acc[P][d] += dpp2<0x4E>(acc[P][d]);
        }
        // lane w==0 writes pair 0, w==1 writes pair 1 (static branches, no runtime indexing)
        float4* comb = (float4*)sC + h * SSP;
#define WRITE_PAIR(P) { \
            const int r0 = 2 * (pbase + (P)); \
            if (r0 < SS) { \
                const float ix = 1.f / l[P].x; \
                comb[r0] = make_float4(acc[P][0].x*ix, acc[P][1].x*ix, \
                                       acc[P][2].x*ix, acc[P][3].x*ix); \
            } \
            if (r0 + 1 < SS) { \
                const float iy = 1.f / l[P].y; \
                comb[r0+1] = make_float4(acc[P][0].y*iy, acc[P][1].y*iy, \
                                         acc[P][2].y*iy, acc[P][3].y*iy); \
            } \
        }
        if      (w == 0) WRITE_PAIR(0)
        else if (w == 1) WRITE_PAIR(1)
#undef WRITE_PAIR
    }
    __syncthreads();

    // ---------------- phase 3: output projection (wo in SGPRs) ----------------
    const int row = wid * 26 + lane;
    if (lane < 26 && row < SS) {
        const float4 c0 = ((const float4*)sC)[row];        // head 0
        const float4 c1 = ((const float4*)sC)[SSP + row];  // head 1
        float o[8];
#pragma unroll
        for (int i = 0; i < 8; ++i) {
            const float* wr = wo + i*8;
            o[i] = c0.x*wr[0] + c0.y*wr[1] + c0.z*wr[2] + c0.w*wr[3]
                 + c1.x*wr[4] + c1.y*wr[5] + c1.z*wr[6] + c1.w*wr[7];
        }
        float4* o4 = (float4*)(out + (size_t)b * (SS * HID) + row * HID);
        o4[0] = make_float4(o[0], o[1], o[2], o[3]);
        o4[1] = make_float4(o[4], o[5], o[6], o[7]);
    }
}

extern "C" void kernel_launch(void* const* d_in, const int* in_sizes, int n_in,
                              void* d_out, int out_size, void* d_ws, size_t ws_size,
                              hipStream_t stream) {
    const float* query = (const float*)d_in[0];
    const float* key   = (const float*)d_in[1];
    const float* value = (const float*)d_in[2];
    const float* wq    = (const float*)d_in[3];
    const float* wk    = (const float*)d_in[4];
    const float* wv    = (const float*)d_in[5];
    const float* wo    = (const float*)d_in[6];
    float* out = (float*)d_out;
    mha_fused_kernel<<<NB, 256, 0, stream>>>(query, key, value, wq, wk, wv, wo, out);
}

// Round 3
// 129.073 us; speedup vs baseline: 4.5739x; 1.0905x over previous
//
#include <hip/hip_runtime.h>

#define NB   4096
#define SS   102
#define SSP  104
#define HID  8
#define NH   2
#define HD   4
#define RS   0.72134752044448170368f   // 0.5 * log2(e): score scale folded into q

typedef float v2f __attribute__((ext_vector_type(2)));

// K/V row permutation, bijective on [0,104): keys 8j+w land at 13w+j ->
// a wave's 4 key-residue lanes read 4 bank-spread addresses (verified conflict-free).
__device__ __forceinline__ int PIDX(int r) { return (r & 7) * 13 + (r >> 3); }
// q pair permutation, bijective on [0,52): spreads phase-2 q reads across bank groups.
__device__ __forceinline__ int PJ(int p) { return (p & 3) * 13 + (p >> 2); }

template<int CTRL>
__device__ __forceinline__ float dppf(float x) {
    return __builtin_bit_cast(float,
        __builtin_amdgcn_mov_dpp(__builtin_bit_cast(int, x), CTRL, 0xF, 0xF, true));
}
template<int CTRL>
__device__ __forceinline__ v2f dpp2(v2f x) {
    v2f r; r.x = dppf<CTRL>(x.x); r.y = dppf<CTRL>(x.y); return r;
}

// 8 projected dims for 2 rows (v2f across rows). W is a wave-uniform kernel-arg
// pointer with compile-time indices -> weights come in via s_load (SGPRs).
__device__ __forceinline__ void proj8(const float4& a0, const float4& a1,
                                      const float4& b0, const float4& b1,
                                      const float* __restrict__ W, v2f x[8]) {
    v2f in[8] = { {a0.x,b0.x},{a0.y,b0.y},{a0.z,b0.z},{a0.w,b0.w},
                  {a1.x,b1.x},{a1.y,b1.y},{a1.z,b1.z},{a1.w,b1.w} };
#pragma unroll
    for (int i = 0; i < 8; ++i) {
        v2f acc = in[0] * W[i*8+0];
#pragma unroll
        for (int j = 1; j < 8; ++j) acc += in[j] * W[i*8+j];
        x[i] = acc;
    }
}

// LDS (~13.3 KB):
//  sQ : [2 heads][52 pairs][2 float4]  rotated+pre-scaled q, pair slot = PJ(pair).
//       float4 2s = dims 0,1 x rows {2p,2p+1}; 2s+1 = dims 2,3.  pair 51 = zero pad
//       (PJ(51)==51, so the pad writes go to slot 51).
//  sK : [2][PIDX(row)][4] rotated k (rows 102,103 zero pad)
//  sV : [2][PIDX(row)][4] projected v (rows 102,103 zero pad)
//  sC : [2][row][4] head-combined attention output, linear rows
__global__ __launch_bounds__(256) void mha_fused_kernel(
    const float* __restrict__ query, const float* __restrict__ key,
    const float* __restrict__ value, const float* __restrict__ wq,
    const float* __restrict__ wk, const float* __restrict__ wv,
    const float* __restrict__ wo, float* __restrict__ out)
{
    __shared__ float sQ[NH * 52 * 8];       // 832 floats
    __shared__ float sK[NH * SSP * HD];     // 832
    __shared__ float sV[NH * SSP * HD];     // 832
    __shared__ float sC[NH * SSP * HD];     // 832

    const int t    = threadIdx.x;
    const int b    = blockIdx.x;
    const int wid  = t >> 6;
    const int lane = t & 63;

    // ---------------- phase 0: issue global row loads; zero pads (wave 3) ----------------
    float4 a0, a1, b0, b1;
    if (wid < 3 && lane < 51) {
        const float* src = (wid == 0) ? query : (wid == 1) ? key : value;
        const float4* s4 = (const float4*)(src + (size_t)b * (SS * HID));
        a0 = s4[4*lane]; a1 = s4[4*lane+1]; b0 = s4[4*lane+2]; b1 = s4[4*lane+3];
    }
    if (t >= 208) {
        const int z = t - 208;                 // 0..47
        if (z < 16) {                          // q pad pair 51 (rows 102,103), both heads
            sQ[(z >> 3) * 416 + 408 + (z & 7)] = 0.f;
        } else {                               // k/v pad rows 102,103
            const int rem = z & 15;
            const int h = rem >> 3, r = SS + ((rem >> 2) & 1), d = rem & 3;
            float* dst = (z < 32) ? sK : sV;
            dst[(h * SSP + PIDX(r)) * HD + d] = 0.f;
        }
    }
    // NO barrier: phase 1 depends only on this lane's registers + SGPR weights;
    // pad writes are ordered by the barrier after phase 1 (addresses disjoint).

    // ---------------- phase 1: projections (wave0: q+rot, wave1: k+rot, wave2: v) ----------
    if (wid < 3 && lane < 51) {
        const int r0 = 2 * lane;
        // per-lane trig (waves 0,1 only) — computes while the global loads are in flight
        v2f sn, cs;
        if (wid < 2) {
            const float f0 = (float)r0, f1 = (float)(r0 + 1);
            sn = (v2f){ sinf(f0), sinf(f1) };
            cs = (v2f){ cosf(f0), cosf(f1) };
            if (wid == 0) { sn *= RS; cs *= RS; }
        }
        v2f x[8];
        if (wid == 0)      proj8(a0, a1, b0, b1, wq, x);
        else if (wid == 1) proj8(a0, a1, b0, b1, wk, x);
        else               proj8(a0, a1, b0, b1, wv, x);

        if (wid < 2) {
            // reference broadcast quirk: head0 scaled by sin(s), head1 by cos(s);
            // pair: e' = (e - o)*w, o' = (o + e)*w.  q additionally folds 0.5*log2(e).
            const v2f y0 = (x[0]-x[1])*sn, y1 = (x[1]+x[0])*sn;
            const v2f y2 = (x[2]-x[3])*sn, y3 = (x[3]+x[2])*sn;
            const v2f y4 = (x[4]-x[5])*cs, y5 = (x[5]+x[4])*cs;
            const v2f y6 = (x[6]-x[7])*cs, y7 = (x[7]+x[6])*cs;
            if (wid == 0) {
                const int pj = PJ(lane);            // permuted pair slot
                float4* d = (float4*)sQ;
                d[2*pj]       = make_float4(y0.x, y0.y, y1.x, y1.y);
                d[2*pj+1]     = make_float4(y2.x, y2.y, y3.x, y3.y);
                d[104+2*pj]   = make_float4(y4.x, y4.y, y5.x, y5.y);
                d[104+2*pj+1] = make_float4(y6.x, y6.y, y7.x, y7.y);
            } else {
                const int i0 = PIDX(r0), i1 = PIDX(r0 + 1);
                float4* d = (float4*)sK;
                d[i0]      = make_float4(y0.x, y1.x, y2.x, y3.x);
                d[SSP+i0]  = make_float4(y4.x, y5.x, y6.x, y7.x);
                d[i1]      = make_float4(y0.y, y1.y, y2.y, y3.y);
                d[SSP+i1]  = make_float4(y4.y, y5.y, y6.y, y7.y);
            }
        } else {
            const int i0 = PIDX(r0), i1 = PIDX(r0 + 1);
            float4* d = (float4*)sV;
            d[i0]      = make_float4(x[0].x, x[1].x, x[2].x, x[3].x);
            d[SSP+i0]  = make_float4(x[4].x, x[5].x, x[6].x, x[7].x);
            d[i1]      = make_float4(x[0].y, x[1].y, x[2].y, x[3].y);
            d[SSP+i1]  = make_float4(x[4].y, x[5].y, x[6].y, x[7].y);
        }
    }
    __syncthreads();

    // ---------------- phase 2: attention, ALL 4 waves. wave = (head, q-half) -------------
    // lane = (qp, w): qp = lane>>2 (0..12) owns q-pairs {qh*26+2qp, +1} (4 rows);
    // w = lane&3 owns keys == w (mod 4): 13 iters x 2 keys, conflict-free spread reads.
    // Rotating prefetch: j+1's K/V load while computing j (hides ~120cy LDS latency).
    const int qp = lane >> 2, w = lane & 3;
    if (qp < 13) {
        const int h  = wid >> 1;
        const int qh = wid & 1;
        const int p0 = qh * 26 + 2 * qp;          // first of 2 pairs
        v2f q[2][4];
        {
            const float4* Q4 = (const float4*)sQ + h * 104;
            const int s0 = PJ(p0), s1 = PJ(p0 + 1);
            {
                const float4 f0 = Q4[2*s0], f1 = Q4[2*s0+1];
                q[0][0] = (v2f){f0.x, f0.y}; q[0][1] = (v2f){f0.z, f0.w};
                q[0][2] = (v2f){f1.x, f1.y}; q[0][3] = (v2f){f1.z, f1.w};
            }
            {
                const float4 f0 = Q4[2*s1], f1 = Q4[2*s1+1];
                q[1][0] = (v2f){f0.x, f0.y}; q[1][1] = (v2f){f0.z, f0.w};
                q[1][2] = (v2f){f1.x, f1.y}; q[1][3] = (v2f){f1.z, f1.w};
            }
        }
        v2f acc[2][4], l[2];
#pragma unroll
        for (int P = 0; P < 2; ++P) {
            l[P] = (v2f){0.f, 0.f};
#pragma unroll
            for (int d = 0; d < 4; ++d) acc[P][d] = (v2f){0.f, 0.f};
        }
        const float4* Ka = (const float4*)sK + h*SSP + 13*w;   // keys 8j+w   -> PIDX = 13w+j
        const float4* Kb = Ka + 52;                            // keys 8j+4+w -> PIDX = 13(w+4)+j
        const float4* Va = (const float4*)sV + h*SSP + 13*w;
        const float4* Vb = Va + 52;
        float4 ka = Ka[0], kb = Kb[0], va = Va[0], vb = Vb[0];
#define BODY(KA, KB, VA, VB) { \
            _Pragma("unroll") \
            for (int P = 0; P < 2; ++P) { \
                v2f s = q[P][0]*(KA).x + q[P][1]*(KA).y + q[P][2]*(KA).z + q[P][3]*(KA).w; \
                v2f p; p.x = __builtin_amdgcn_exp2f(s.x); p.y = __builtin_amdgcn_exp2f(s.y); \
                l[P] += p; \
                acc[P][0] += p*(VA).x; acc[P][1] += p*(VA).y; \
                acc[P][2] += p*(VA).z; acc[P][3] += p*(VA).w; \
            } \
            _Pragma("unroll") \
            for (int P = 0; P < 2; ++P) { \
                v2f s = q[P][0]*(KB).x + q[P][1]*(KB).y + q[P][2]*(KB).z + q[P][3]*(KB).w; \
                v2f p; p.x = __builtin_amdgcn_exp2f(s.x); p.y = __builtin_amdgcn_exp2f(s.y); \
                l[P] += p; \
                acc[P][0] += p*(VB).x; acc[P][1] += p*(VB).y; \
                acc[P][2] += p*(VB).z; acc[P][3] += p*(VB).w; \
            } \
        }
        for (int j = 0; j < 12; ++j) {
            const float4 nka = Ka[j+1], nkb = Kb[j+1];
            const float4 nva = Va[j+1], nvb = Vb[j+1];
            BODY(ka, kb, va, vb);
            ka = nka; kb = nkb; va = nva; vb = nvb;
        }
        BODY(ka, kb, va, vb);
#undef BODY
        // pad keys 102 (w=2, Kb) and 103 (w=3, Kb): zero K rows -> exp2(0)=1 leaked into l
        if (w >= 2) { l[0] -= (v2f){1.f, 1.f}; l[1] -= (v2f){1.f, 1.f}; }
        // quad butterfly over the 4 key residues (pure VALU, no LDS round-trip)
#pragma unroll
        for (int P = 0; P < 2; ++P) {
            l[P] += dpp2<0xB1>(l[P]);                       // quad_perm [1,0,3,2]
#pragma unroll
            for (int d = 0; d < 4; ++d) acc[P][d] += dpp2<0xB1>(acc[P][d]);
        }
#pragma unroll
        for (int P = 0; P < 2; ++P) {
            l[P] += dpp2<0x4E>(l[P]);                       // quad_perm [2,3,0,1]
#pragma unroll
            for (int d = 0; d < 4; ++d) acc[P][d] += dpp2<0x4E>(acc[P][d]);
        }
        // lane w==0 writes pair 0, w==1 writes pair 1 (static branches)
        float4* comb = (float4*)sC + h * SSP;
#define WRITE_PAIR(P) { \
            const int r0 = 2 * (p0 + (P)); \
            if (r0 < SS) { \
                const float ix = 1.f / l[P].x; \
                comb[r0] = make_float4(acc[P][0].x*ix, acc[P][1].x*ix, \
                                       acc[P][2].x*ix, acc[P][3].x*ix); \
            } \
            if (r0 + 1 < SS) { \
                const float iy = 1.f / l[P].y; \
                comb[r0+1] = make_float4(acc[P][0].y*iy, acc[P][1].y*iy, \
                                         acc[P][2].y*iy, acc[P][3].y*iy); \
            } \
        }
        if      (w == 0) WRITE_PAIR(0)
        else if (w == 1) WRITE_PAIR(1)
#undef WRITE_PAIR
    }
    __syncthreads();

    // ---------------- phase 3: output projection (wo in SGPRs) ----------------
    const int row = wid * 26 + lane;
    if (lane < 26 && row < SS) {
        const float4 c0 = ((const float4*)sC)[row];        // head 0
        const float4 c1 = ((const float4*)sC)[SSP + row];  // head 1
        float o[8];
#pragma unroll
        for (int i = 0; i < 8; ++i) {
            const float* wr = wo + i*8;
            o[i] = c0.x*wr[0] + c0.y*wr[1] + c0.z*wr[2] + c0.w*wr[3]
                 + c1.x*wr[4] + c1.y*wr[5] + c1.z*wr[6] + c1.w*wr[7];
        }
        float4* o4 = (float4*)(out + (size_t)b * (SS * HID) + row * HID);
        o4[0] = make_float4(o[0], o[1], o[2], o[3]);
        o4[1] = make_float4(o[4], o[5], o[6], o[7]);
    }
}

extern "C" void kernel_launch(void* const* d_in, const int* in_sizes, int n_in,
                              void* d_out, int out_size, void* d_ws, size_t ws_size,
                              hipStream_t stream) {
    const float* query = (const float*)d_in[0];
    const float* key   = (const float*)d_in[1];
    const float* value = (const float*)d_in[2];
    const float* wq    = (const float*)d_in[3];
    const float* wk    = (const float*)d_in[4];
    const float* wv    = (const float*)d_in[5];
    const float* wo    = (const float*)d_in[6];
    float* out = (float*)d_out;
    mha_fused_kernel<<<NB, 256, 0, stream>>>(query, key, value, wq, wk, wv, wo, out);
}